// Round 1
// baseline (1169.885 us; speedup 1.0000x reference)
//
#include <hip/hip_runtime.h>
#include <hip/hip_bf16.h>

#define N_NODES 16384
#define HID 128

typedef float f32x4 __attribute__((ext_vector_type(4)));
typedef __bf16 bf16x8 __attribute__((ext_vector_type(8)));

__global__ void zero_i32(int* __restrict__ p, int n) {
    int i = blockIdx.x * blockDim.x + threadIdx.x;
    if (i < n) p[i] = 0;
}

// counts[t] = number of edges with target t
__global__ void count_k(const int* __restrict__ col, int* __restrict__ counts, int E) {
    int e = blockIdx.x * blockDim.x + threadIdx.x;
    if (e < E) atomicAdd(&counts[col[e]], 1);
}

// Single-block exclusive scan over 16384 counts; also emits cursors and dinv=rsqrt(deg)
__global__ __launch_bounds__(256) void scan_k(const int* __restrict__ counts,
                                              int* __restrict__ offsets,
                                              int* __restrict__ cursor,
                                              float* __restrict__ dinv) {
    __shared__ int part[256];
    int t = threadIdx.x;
    const int PER = N_NODES / 256;  // 64
    int base = t * PER;
    int s = 0;
    for (int i = 0; i < PER; i++) s += counts[base + i];
    part[t] = s;
    __syncthreads();
    for (int off = 1; off < 256; off <<= 1) {
        int v = (t >= off) ? part[t - off] : 0;
        __syncthreads();
        part[t] += v;
        __syncthreads();
    }
    int run = (t > 0) ? part[t - 1] : 0;
    for (int i = 0; i < PER; i++) {
        int c = counts[base + i];
        offsets[base + i] = run;
        cursor[base + i] = run;
        dinv[base + i] = rsqrtf((float)(c + 1));  // +1 self-loop; deg>=1 always
        run += c;
    }
    if (t == 255) offsets[N_NODES] = run;
}

// bucket[offsets[c] .. offsets[c+1]) = source rows of edges targeting c
__global__ void scatter_k(const int* __restrict__ row, const int* __restrict__ col,
                          int* __restrict__ cursor, int* __restrict__ bucket, int E) {
    int e = blockIdx.x * blockDim.x + threadIdx.x;
    if (e < E) {
        int c = col[e];
        int p = atomicAdd(&cursor[c], 1);
        bucket[p] = row[e];
    }
}

// h1 = x @ W  (fp32, 0.54 GFLOP — VALU is fine)
__global__ __launch_bounds__(256) void xw_k(const float* __restrict__ x,
                                            const float* __restrict__ W,
                                            float* __restrict__ h1) {
    __shared__ float xs[2][HID];
    int r = threadIdx.x >> 7;          // 0..1 local row
    int c = threadIdx.x & 127;         // output column
    int node = blockIdx.x * 2 + r;
    xs[r][c] = x[node * HID + c];
    __syncthreads();
    float acc = 0.f;
#pragma unroll 8
    for (int k = 0; k < HID; k++) acc = fmaf(xs[r][k], W[k * HID + c], acc);
    h1[node * HID + c] = acc;
}

// out[n] = relu( dn*(dn*h1[n] + sum_{r in in(n)} dinv[r]*h1[r]) + b ) -> bf16
__global__ __launch_bounds__(128) void agg_k(const float* __restrict__ h1,
                                             const int* __restrict__ offsets,
                                             const int* __restrict__ bucket,
                                             const float* __restrict__ dinv,
                                             const float* __restrict__ bias,
                                             __hip_bfloat16* __restrict__ hb) {
    __shared__ int rs[128];
    __shared__ float dsh[128];
    int n = blockIdx.x, c = threadIdx.x;
    float dn = dinv[n];
    float acc = dn * h1[n * HID + c];   // self-loop term (dn factor applied at end)
    int s = offsets[n], e = offsets[n + 1];
    for (int base = s; base < e; base += 128) {
        int m = e - base;
        if (m > 128) m = 128;
        __syncthreads();
        if (c < m) {
            int r = bucket[base + c];
            rs[c] = r;
            dsh[c] = dinv[r];
        }
        __syncthreads();
        for (int i = 0; i < m; i++) acc = fmaf(dsh[i], h1[rs[i] * HID + c], acc);
    }
    acc = fmaf(dn, acc, bias[c]);
    acc = fmaxf(acc, 0.f);
    hb[n * HID + c] = __float2bfloat16(acc);
}

// out = hb @ hb^T, fp32 out. 128x128 tile/block, K=128 in one LDS stage,
// 4 k-steps of mfma_f32_16x16x32_bf16. Write-bound (1 GiB fp32 out).
__global__ __launch_bounds__(256) void gemm2_k(const __hip_bfloat16* __restrict__ hbp,
                                               float* __restrict__ out) {
    __shared__ ushort As[128][136];  // +8 pad: even bank distribution for b128 reads
    __shared__ ushort Bs[128][136];
    const ushort* hb = (const ushort*)hbp;
    int i0 = blockIdx.y * 128, j0 = blockIdx.x * 128;
    int tid = threadIdx.x;
#pragma unroll
    for (int p = 0; p < 8; p++) {
        int lin = p * 256 + tid;
        int r = lin >> 4;             // 16 threads/row, 8 shorts each
        int ch = (lin & 15) * 8;
        *(int4*)&As[r][ch] = *(const int4*)&hb[(i0 + r) * HID + ch];
        *(int4*)&Bs[r][ch] = *(const int4*)&hb[(j0 + r) * HID + ch];
    }
    __syncthreads();

    int lane = tid & 63, w = tid >> 6;
    int wm = (w >> 1) * 64, wn = (w & 1) * 64;  // 2x2 waves, each 64x64
    int lr = lane & 15, lg = lane >> 4;

    f32x4 acc[4][4];
#pragma unroll
    for (int a = 0; a < 4; a++)
#pragma unroll
        for (int bq = 0; bq < 4; bq++) acc[a][bq] = f32x4{0.f, 0.f, 0.f, 0.f};

#pragma unroll
    for (int ks = 0; ks < 4; ks++) {
        bf16x8 af[4], bf[4];
#pragma unroll
        for (int t = 0; t < 4; t++) {
            af[t] = *(const bf16x8*)&As[wm + t * 16 + lr][ks * 32 + lg * 8];
            bf[t] = *(const bf16x8*)&Bs[wn + t * 16 + lr][ks * 32 + lg * 8];
        }
#pragma unroll
        for (int tm = 0; tm < 4; tm++)
#pragma unroll
            for (int tn = 0; tn < 4; tn++)
                acc[tm][tn] = __builtin_amdgcn_mfma_f32_16x16x32_bf16(af[tm], bf[tn],
                                                                      acc[tm][tn], 0, 0, 0);
    }

    // C/D layout: col = lane&15, row = (lane>>4)*4 + reg
#pragma unroll
    for (int tm = 0; tm < 4; tm++) {
        int rbase = i0 + wm + tm * 16 + lg * 4;
#pragma unroll
        for (int tn = 0; tn < 4; tn++) {
            int cc = j0 + wn + tn * 16 + lr;
#pragma unroll
            for (int r = 0; r < 4; r++)
                out[(size_t)(rbase + r) * N_NODES + cc] = acc[tm][tn][r];
        }
    }
}

extern "C" void kernel_launch(void* const* d_in, const int* in_sizes, int n_in,
                              void* d_out, int out_size, void* d_ws, size_t ws_size,
                              hipStream_t stream) {
    const float* x = (const float*)d_in[0];
    const int* ei = (const int*)d_in[1];
    const float* W = (const float*)d_in[2];
    const float* b = (const float*)d_in[3];
    float* out = (float*)d_out;
    int E = in_sizes[1] / 2;           // edge_index is [2, E]
    const int* row = ei;               // sources
    const int* col = ei + E;           // targets

    char* ws = (char*)d_ws;
    int* counts        = (int*)(ws);                    // 64 KB
    int* offsets       = (int*)(ws + (64 << 10));       // 64 KB + 4
    int* cursor        = (int*)(ws + (136 << 10));      // 64 KB
    float* dinv        = (float*)(ws + (200 << 10));    // 64 KB
    float* h1          = (float*)(ws + (1 << 20));      // 8 MB
    __hip_bfloat16* hb = (__hip_bfloat16*)(ws + (9 << 20));   // 4 MB
    int* bucket        = (int*)(ws + (13 << 20));       // E*4 = 2 MB

    zero_i32<<<64, 256, 0, stream>>>(counts, N_NODES);
    count_k<<<(E + 255) / 256, 256, 0, stream>>>(col, counts, E);
    scan_k<<<1, 256, 0, stream>>>(counts, offsets, cursor, dinv);
    xw_k<<<N_NODES / 2, 256, 0, stream>>>(x, W, h1);
    scatter_k<<<(E + 255) / 256, 256, 0, stream>>>(row, col, cursor, bucket, E);
    agg_k<<<N_NODES, 128, 0, stream>>>(h1, offsets, bucket, dinv, b, hb);
    gemm2_k<<<dim3(128, 128), 256, 0, stream>>>(hb, out);
}